// Round 2
// baseline (791.854 us; speedup 1.0000x reference)
//
#include <hip/hip_runtime.h>
#include <math.h>

namespace {

constexpr int BB = 2;
constexpr int HH = 160;
constexpr int WW = 160;
constexpr int DD = 160;
constexpr int NV = BB * HH * WW * DD;   // 8,192,000
constexpr int RAD = 4;                  // window 9
constexpr float WVOL = 729.0f;          // (729.0 + 1e-5) rounds to 729.0f in f32
constexpr float EPSF = 1e-5f;

constexpr int SW = DD;            // stride along w
constexpr int SH = WW * DD;       // stride along h

// ---------------- K1: 9-tap box along d for the two inputs ----------------
__global__ void k1_box_d(const float* __restrict__ t, const float* __restrict__ p,
                         float* __restrict__ st, float* __restrict__ sp) {
    int idx = blockIdx.x * blockDim.x + threadIdx.x;
    if (idx >= NV) return;
    int d = idx % DD;
    int lo = -min(d, RAD), hi = min(DD - 1 - d, RAD);
    float a = 0.f, b = 0.f;
    for (int k = lo; k <= hi; ++k) {
        a += t[idx + k];
        b += p[idx + k];
    }
    st[idx] = a; sp[idx] = b;
}

// ---------------- K2: 9-tap box along w for two fields ----------------
__global__ void k2_box_w(const float* __restrict__ st, const float* __restrict__ sp,
                         float* __restrict__ st2, float* __restrict__ sp2) {
    int idx = blockIdx.x * blockDim.x + threadIdx.x;
    if (idx >= NV) return;
    int w = (idx / SW) % WW;
    int lo = -min(w, RAD), hi = min(WW - 1 - w, RAD);
    float a = 0.f, b = 0.f;
    for (int k = lo; k <= hi; ++k) {
        a += st[idx + k * SW];
        b += sp[idx + k * SW];
    }
    st2[idx] = a; sp2[idx] = b;
}

// ---------------- K3: 9-tap box along h, divide by 729 -> means ----------------
__global__ void k3_box_h_mean(const float* __restrict__ st2, const float* __restrict__ sp2,
                              float* __restrict__ mt, float* __restrict__ mp) {
    int idx = blockIdx.x * blockDim.x + threadIdx.x;
    if (idx >= NV) return;
    int h = (idx / SH) % HH;
    int lo = -min(h, RAD), hi = min(HH - 1 - h, RAD);
    float a = 0.f, b = 0.f;
    for (int k = lo; k <= hi; ++k) {
        a += st2[idx + k * SH];
        b += sp2[idx + k * SH];
    }
    mt[idx] = a / WVOL; mp[idx] = b / WVOL;
}

// ---------------- K4: q = (td*td, pd*pd, td*pd) on the fly, box along d ----------------
__global__ void k4_q_box_d(const float* __restrict__ t, const float* __restrict__ p,
                           const float* __restrict__ mt, const float* __restrict__ mp,
                           float* __restrict__ a1, float* __restrict__ b1,
                           float* __restrict__ c1) {
    int idx = blockIdx.x * blockDim.x + threadIdx.x;
    if (idx >= NV) return;
    int d = idx % DD;
    int lo = -min(d, RAD), hi = min(DD - 1 - d, RAD);
    float sa = 0.f, sb = 0.f, sc = 0.f;
    for (int k = lo; k <= hi; ++k) {
        int j = idx + k;
        float td = t[j] - mt[j];
        float pd = p[j] - mp[j];
        sa += td * td;
        sb += pd * pd;
        sc += td * pd;
    }
    a1[idx] = sa; b1[idx] = sb; c1[idx] = sc;
}

// ---------------- K5: box along w for three fields ----------------
__global__ void k5_box_w3(const float* __restrict__ a1, const float* __restrict__ b1,
                          const float* __restrict__ c1,
                          float* __restrict__ a2, float* __restrict__ b2,
                          float* __restrict__ c2) {
    int idx = blockIdx.x * blockDim.x + threadIdx.x;
    if (idx >= NV) return;
    int w = (idx / SW) % WW;
    int lo = -min(w, RAD), hi = min(WW - 1 - w, RAD);
    float sa = 0.f, sb = 0.f, sc = 0.f;
    for (int k = lo; k <= hi; ++k) {
        int j = idx + k * SW;
        sa += a1[j]; sb += b1[j]; sc += c1[j];
    }
    a2[idx] = sa; b2[idx] = sb; c2[idx] = sc;
}

// ---------------- K6: box along h for three fields + cc + reduce ----------------
__global__ void k6_box_h3_cc_reduce(const float* __restrict__ a2, const float* __restrict__ b2,
                                    const float* __restrict__ c2,
                                    double* __restrict__ acc) {
    int idx = blockIdx.x * blockDim.x + threadIdx.x;
    double v = 0.0;
    if (idx < NV) {
        int h = (idx / SH) % HH;
        int lo = -min(h, RAD), hi = min(HH - 1 - h, RAD);
        float sa = 0.f, sb = 0.f, sc = 0.f;
        for (int k = lo; k <= hi; ++k) {
            int j = idx + k * SH;
            sa += a2[j]; sb += b2[j]; sc += c2[j];
        }
        float cc = sc / sqrtf((sa + EPSF) * (sb + EPSF));
        v = (double)cc;
    }
    // wave reduce (64 lanes)
    for (int off = 32; off > 0; off >>= 1)
        v += __shfl_down(v, off, 64);
    __shared__ double red[4];
    int lane = threadIdx.x & 63;
    int wv = threadIdx.x >> 6;
    if (lane == 0) red[wv] = v;
    __syncthreads();
    if (threadIdx.x == 0) {
        double s = red[0] + red[1] + red[2] + red[3];
        atomicAdd(acc, s);
    }
}

// ---------------- K7: finalize ----------------
__global__ void k7_finalize(const double* __restrict__ acc, float* __restrict__ out) {
    out[0] = -(float)(acc[0] / (double)NV);
}

} // anonymous namespace

extern "C" void kernel_launch(void* const* d_in, const int* in_sizes, int n_in,
                              void* d_out, int out_size, void* d_ws, size_t ws_size,
                              hipStream_t stream) {
    const float* t = (const float*)d_in[0];
    const float* p = (const float*)d_in[1];
    float* out = (float*)d_out;

    char* ws = (char*)d_ws;
    double* acc = (double*)ws;
    float* F0 = (float*)(ws + 256);
    float* F1 = F0 + NV;
    float* F2 = F1 + NV;
    float* F3 = F2 + NV;
    float* F4 = F3 + NV;
    float* F5 = F4 + NV;

    hipMemsetAsync(acc, 0, sizeof(double), stream);

    const int BLK = 256;
    const int GRD = (NV + BLK - 1) / BLK;   // 32000, exact

    // K1: box_d(t), box_d(p) -> F0, F1
    k1_box_d<<<GRD, BLK, 0, stream>>>(t, p, F0, F1);
    // K2: box_w -> F2, F3
    k2_box_w<<<GRD, BLK, 0, stream>>>(F0, F1, F2, F3);
    // K3: box_h, /729 -> means in F0, F1 (st/sp dead)
    k3_box_h_mean<<<GRD, BLK, 0, stream>>>(F2, F3, F0, F1);
    // K4: q-fields boxed along d -> F2, F3, F4 (st2/sp2 dead)
    k4_q_box_d<<<GRD, BLK, 0, stream>>>(t, p, F0, F1, F2, F3, F4);
    // K5: box_w of q -> F0, F1, F5 (means dead)
    k5_box_w3<<<GRD, BLK, 0, stream>>>(F2, F3, F4, F0, F1, F5);
    // K6: box_h of q + cc + reduce
    k6_box_h3_cc_reduce<<<GRD, BLK, 0, stream>>>(F0, F1, F5, acc);
    // K7: finalize
    k7_finalize<<<1, 1, 0, stream>>>(acc, out);
}

// Round 6
// 448.538 us; speedup vs baseline: 1.7654x; 1.7654x over previous
//
#include <hip/hip_runtime.h>
#include <math.h>

namespace {

constexpr int BB = 2;
constexpr int HH = 160;
constexpr int WW = 160;
constexpr int DD = 160;
constexpr int NV = BB * HH * WW * DD;   // 8,192,000
constexpr int RAD = 4;                  // window 9
constexpr float WVOL = 729.0f;          // (729.0 + 1e-5) rounds to 729.0f in f32
constexpr float EPSF = 1e-5f;

constexpr int SH = WW * DD;       // stride along h (25600)
constexpr int NSLICE = BB * HH;   // 320 (w,d) slices

constexpr int BLK = 256;
constexpr int GRD = NV / BLK;     // 32000 (exact) — used by k6/k7

// ---------------- K12: fused 9-tap box along d then w, two fields ----------------
// One block = one (b,h) slice x one 32-wide d-chunk. LDS: 160x40 in + 160x32 dbox.
__global__ __launch_bounds__(256) void k12_box_dw(const float* __restrict__ t,
                                                  const float* __restrict__ p,
                                                  float* __restrict__ st2,
                                                  float* __restrict__ sp2) {
    __shared__ float sIn[160 * 40];
    __shared__ float sDb[160 * 32];
    int chunk = blockIdx.x % 5;       // 5 chunks of 32 along d
    int slice = blockIdx.x / 5;       // 0..319
    int base = slice * SH;
    int d0 = chunk * 32;

    for (int f = 0; f < 2; ++f) {
        const float* src = f ? p : t;
        float* dst = f ? sp2 : st2;
        // load halo'd tile (zero-fill outside volume = zero padding)
        for (int li = threadIdx.x; li < 160 * 40; li += 256) {
            int w = li / 40, di = li % 40;
            int gd = d0 + di - RAD;
            float v = 0.f;
            if ((unsigned)gd < (unsigned)DD) v = src[base + w * DD + gd];
            sIn[li] = v;
        }
        __syncthreads();
        // 9-tap box along d
        for (int oi = threadIdx.x; oi < 160 * 32; oi += 256) {
            int w = oi / 32, dd = oi % 32;
            const float* r = &sIn[w * 40 + dd];
            float s = 0.f;
#pragma unroll
            for (int k = 0; k < 9; ++k) s += r[k];
            sDb[oi] = s;
        }
        __syncthreads();
        // 9-tap box along w (predicated, zero outside) + store
        for (int oi = threadIdx.x; oi < 160 * 32; oi += 256) {
            int w = oi / 32, dd = oi % 32;
            float s = 0.f;
#pragma unroll
            for (int j = -RAD; j <= RAD; ++j) {
                bool ok = (unsigned)(w + j) < (unsigned)WW;
                int wj = ok ? (w + j) : 0;
                s += ok ? sDb[wj * 32 + dd] : 0.f;
            }
            dst[base + w * DD + d0 + dd] = s;
        }
        __syncthreads();
    }
}

// ---------------- K3: 9-tap box along h, divide by 729 -> means ----------------
__global__ void k3_box_h_mean(const float* __restrict__ st2, const float* __restrict__ sp2,
                              float* __restrict__ mt, float* __restrict__ mp) {
    int idx = blockIdx.x * blockDim.x + threadIdx.x;
    int h = (idx / SH) % HH;
    float a = 0.f, b = 0.f;
#pragma unroll
    for (int k = -RAD; k <= RAD; ++k) {
        bool ok = (unsigned)(h + k) < (unsigned)HH;
        int j = idx + (ok ? k : 0) * SH;
        a += ok ? st2[j] : 0.f;
        b += ok ? sp2[j] : 0.f;
    }
    mt[idx] = a / WVOL; mp[idx] = b / WVOL;
}

// ---------------- K45: q=(td*td,pd*pd,td*pd) + fused d+w box, three fields ----------------
// One block = one (b,h) slice x one 16-wide d-chunk. LDS: 3x(160x24) q-tiles + 160x16 dbox.
__global__ __launch_bounds__(256) void k45_q_box_dw(const float* __restrict__ t,
                                                    const float* __restrict__ p,
                                                    const float* __restrict__ mt,
                                                    const float* __restrict__ mp,
                                                    float* __restrict__ a2,
                                                    float* __restrict__ b2,
                                                    float* __restrict__ c2) {
    __shared__ float sA[160 * 24];
    __shared__ float sB[160 * 24];
    __shared__ float sC[160 * 24];
    __shared__ float sDb[160 * 16];
    int chunk = blockIdx.x % 10;      // 10 chunks of 16 along d
    int slice = blockIdx.x / 10;
    int base = slice * SH;
    int d0 = chunk * 16;

    // load q tiles (halo'd along d, zero outside)
    for (int li = threadIdx.x; li < 160 * 24; li += 256) {
        int w = li / 24, di = li % 24;
        int gd = d0 + di - RAD;
        float va = 0.f, vb = 0.f, vc = 0.f;
        if ((unsigned)gd < (unsigned)DD) {
            int g = base + w * DD + gd;
            float td = t[g] - mt[g];
            float pd = p[g] - mp[g];
            va = td * td; vb = pd * pd; vc = td * pd;
        }
        sA[li] = va; sB[li] = vb; sC[li] = vc;
    }
    __syncthreads();

    for (int f = 0; f < 3; ++f) {
        const float* sQ = (f == 0) ? sA : (f == 1) ? sB : sC;
        float* dst = (f == 0) ? a2 : (f == 1) ? b2 : c2;
        // d-box
        for (int oi = threadIdx.x; oi < 160 * 16; oi += 256) {
            int w = oi / 16, dd = oi % 16;
            const float* r = &sQ[w * 24 + dd];
            float s = 0.f;
#pragma unroll
            for (int k = 0; k < 9; ++k) s += r[k];
            sDb[oi] = s;
        }
        __syncthreads();
        // w-box + store
        for (int oi = threadIdx.x; oi < 160 * 16; oi += 256) {
            int w = oi / 16, dd = oi % 16;
            float s = 0.f;
#pragma unroll
            for (int j = -RAD; j <= RAD; ++j) {
                bool ok = (unsigned)(w + j) < (unsigned)WW;
                int wj = ok ? (w + j) : 0;
                s += ok ? sDb[wj * 16 + dd] : 0.f;
            }
            dst[base + w * DD + d0 + dd] = s;
        }
        __syncthreads();
    }
}

// ---------------- K6: box along h for three fields + cc + block partial ----------------
__global__ void k6_box_h3_cc_partial(const float* __restrict__ a2, const float* __restrict__ b2,
                                     const float* __restrict__ c2,
                                     double* __restrict__ partials) {
    int idx = blockIdx.x * blockDim.x + threadIdx.x;
    int h = (idx / SH) % HH;
    float sa = 0.f, sb = 0.f, sc = 0.f;
#pragma unroll
    for (int k = -RAD; k <= RAD; ++k) {
        bool ok = (unsigned)(h + k) < (unsigned)HH;
        int j = idx + (ok ? k : 0) * SH;
        sa += ok ? a2[j] : 0.f;
        sb += ok ? b2[j] : 0.f;
        sc += ok ? c2[j] : 0.f;
    }
    float cc = sc / sqrtf((sa + EPSF) * (sb + EPSF));
    double v = (double)cc;
#pragma unroll
    for (int off = 32; off > 0; off >>= 1)
        v += __shfl_down(v, off, 64);
    __shared__ double red[4];
    int lane = threadIdx.x & 63;
    int wv = threadIdx.x >> 6;
    if (lane == 0) red[wv] = v;
    __syncthreads();
    if (threadIdx.x == 0)
        partials[blockIdx.x] = red[0] + red[1] + red[2] + red[3];
}

// ---------------- K7: reduce 32000 partials + finalize ----------------
__global__ void k7_reduce(const double* __restrict__ partials, float* __restrict__ out) {
    __shared__ double red[256];
    double s = 0.0;
    for (int i = threadIdx.x; i < GRD; i += 256)
        s += partials[i];
    red[threadIdx.x] = s;
    __syncthreads();
    for (int ofs = 128; ofs > 0; ofs >>= 1) {
        if (threadIdx.x < ofs) red[threadIdx.x] += red[threadIdx.x + ofs];
        __syncthreads();
    }
    if (threadIdx.x == 0)
        out[0] = -(float)(red[0] / (double)NV);
}

} // anonymous namespace

extern "C" void kernel_launch(void* const* d_in, const int* in_sizes, int n_in,
                              void* d_out, int out_size, void* d_ws, size_t ws_size,
                              hipStream_t stream) {
    const float* t = (const float*)d_in[0];
    const float* p = (const float*)d_in[1];
    float* out = (float*)d_out;

    char* ws = (char*)d_ws;
    float* F0 = (float*)(ws + 256);
    float* F1 = F0 + NV;
    float* F2 = F1 + NV;
    float* F3 = F2 + NV;
    float* F4 = F3 + NV;
    float* F5 = F4 + NV;

    // K12: fused d+w box of t,p -> F0 (st2), F1 (sp2)
    k12_box_dw<<<NSLICE * 5, BLK, 0, stream>>>(t, p, F0, F1);
    // K3: h-box + /729 -> means F2 (mt), F3 (mp)
    k3_box_h_mean<<<GRD, BLK, 0, stream>>>(F0, F1, F2, F3);
    // K45: q + fused d+w box -> F0 (a2), F1 (b2), F4 (c2)
    k45_q_box_dw<<<NSLICE * 10, BLK, 0, stream>>>(t, p, F2, F3, F0, F1, F4);
    // K6: h-box of q + cc + per-block partials (in F5)
    double* partials = (double*)F5;
    k6_box_h3_cc_partial<<<GRD, BLK, 0, stream>>>(F0, F1, F4, partials);
    // K7: final reduce + negate/mean
    k7_reduce<<<1, 256, 0, stream>>>(partials, out);
}